// Round 12
// baseline (1204.635 us; speedup 1.0000x reference)
//
#include <hip/hip_runtime.h>
#include <math.h>

typedef __attribute__((ext_vector_type(8))) short bf16x8;
typedef __attribute__((ext_vector_type(4))) short bf16x4;
typedef __attribute__((ext_vector_type(4))) float f32x4;

static __device__ __forceinline__ unsigned short f2bf(float x){
    union{float f; unsigned u;} v; v.f = x;
    unsigned r = v.u + 0x7fffu + ((v.u >> 16) & 1u);
    return (unsigned short)(r >> 16);
}
static __device__ __forceinline__ unsigned cvtpk(float lo, float hi){
    unsigned r;
    asm("v_cvt_pk_bf16_f32 %0, %1, %2" : "=v"(r) : "v"(lo), "v"(hi));
    return r;
}
static __device__ __forceinline__ float bflo(unsigned u){
    union{unsigned x; float f;} v; v.x = u << 16; return v.f;
}
static __device__ __forceinline__ float bfhi(unsigned u){
    union{unsigned x; float f;} v; v.x = u & 0xffff0000u; return v.f;
}

// --------------------- QKV (Q,K stored bf16 PERMUTED; V bf16 linear) -------
// perm(d): hh=d>>4, g4=(d>>2)&3, j=d&3 -> p = g4*32 + hh*4 + j
// so lane (eloc,g4) reads its 32 epilogue ushorts contiguously.
__global__ __launch_bounds__(128)
void qkv_kernel(const float* __restrict__ h,
                const float* __restrict__ Wq, const float* __restrict__ Wk,
                const float* __restrict__ Wv,
                unsigned short* __restrict__ Qp16, unsigned short* __restrict__ Kp16,
                unsigned short* __restrict__ Vb16)
{
    __shared__ float hl[16 * 128];
    const int t  = threadIdx.x;
    const int n0 = blockIdx.x * 16;

    const float4* hg4 = (const float4*)(h + (size_t)n0 * 128);
    float4* hl4 = (float4*)hl;
    #pragma unroll
    for (int i = 0; i < 4; ++i) hl4[i * 128 + t] = hg4[i * 128 + t];
    __syncthreads();

    const int pt = ((t >> 2) & 3) * 32 + (t >> 4) * 4 + (t & 3);  // perm(t)

    #pragma unroll
    for (int m = 0; m < 3; ++m) {
        const float* W = (m == 0 ? Wq : (m == 1 ? Wk : Wv)) + t * 128;
        float acc[16];
        #pragma unroll
        for (int n = 0; n < 16; ++n) acc[n] = 0.f;
        for (int kc = 0; kc < 32; ++kc) {
            const float4 w = *(const float4*)(W + kc * 4);
            #pragma unroll
            for (int n = 0; n < 16; ++n) {
                const float4 x = *(const float4*)&hl[n * 128 + kc * 4];
                acc[n] += w.x * x.x + w.y * x.y + w.z * x.z + w.w * x.w;
            }
        }
        unsigned short* o;
        if (m == 0)      o = Qp16 + (size_t)n0 * 128 + pt;
        else if (m == 1) o = Kp16 + (size_t)n0 * 128 + pt;
        else             o = Vb16 + (size_t)n0 * 128 + t;
        #pragma unroll
        for (int n = 0; n < 16; ++n) o[(size_t)n * 128] = f2bf(acc[n]);
    }
}

// ------------------------------------------------------------- CSR build ---
__global__ void hist_kernel(const int* __restrict__ ei, int* __restrict__ cnt, int EDG)
{
    const int stride = gridDim.x * blockDim.x;
    for (int e = blockIdx.x * blockDim.x + threadIdx.x; e < EDG; e += stride)
        atomicAdd(&cnt[ei[EDG + e]], 1);
}

__global__ __launch_bounds__(1024)
void scan_a(const int* __restrict__ cnt, int* __restrict__ bsum, int n)
{
    __shared__ int tmp[1024];
    const int t = threadIdx.x;
    const int i = blockIdx.x * 1024 + t;
    tmp[t] = (i < n) ? cnt[i] : 0;
    __syncthreads();
    for (int d = 512; d > 0; d >>= 1) {
        if (t < d) tmp[t] += tmp[t + d];
        __syncthreads();
    }
    if (t == 0) bsum[blockIdx.x] = tmp[0];
}

__global__ void scan_b(const int* __restrict__ bsum, int* __restrict__ bbase,
                       int* __restrict__ offs, int nb, int n)
{
    if (threadIdx.x == 0) {
        int run = 0;
        for (int b = 0; b < nb; ++b) { bbase[b] = run; run += bsum[b]; }
        offs[n] = run;
    }
}

__global__ __launch_bounds__(1024)
void scan_c(const int* __restrict__ cnt, const int* __restrict__ bbase,
            int* __restrict__ offs, int n)
{
    __shared__ int tmp[1024];
    const int t = threadIdx.x;
    const int i = blockIdx.x * 1024 + t;
    const int v = (i < n) ? cnt[i] : 0;
    tmp[t] = v;
    __syncthreads();
    for (int d = 1; d < 1024; d <<= 1) {
        const int a = (t >= d) ? tmp[t - d] : 0;
        __syncthreads();
        tmp[t] += a;
        __syncthreads();
    }
    if (i < n) offs[i] = bbase[blockIdx.x] + tmp[t] - v;
}

__global__ void scatter_kernel(const int* __restrict__ ei, const int* __restrict__ offs,
                               int* __restrict__ cnt, int2* __restrict__ elist, int EDG)
{
    const int stride = gridDim.x * blockDim.x;
    for (int e = blockIdx.x * blockDim.x + threadIdx.x; e < EDG; e += stride) {
        const int d = ei[EDG + e];
        const int p = atomicSub(&cnt[d], 1) - 1;
        int2 v; v.x = ei[e]; v.y = e;
        elist[offs[d] + p] = v;
    }
}

// --------------------------------------- fused edge-score + gather (MFMA) --
// Address-diet v5: all per-edge gathers are 16B/lane.
//  - eattr: 8x dwordx4 (fp32 input, unavoidable)
//  - K: 4x uint4 from PERMUTED bf16 rows (contiguous per lane)
//  - Q: 4x uint4 per node (permuted bf16)
//  - V: quarter-wave per edge, 1x uint4 per edge (8 dims/lane)
__global__ __launch_bounds__(256, 3)
void fused_attn(const float* __restrict__ eattr, const int2* __restrict__ elist,
                const int* __restrict__ offs,
                const float* __restrict__ We, const float* __restrict__ Wb,
                const float* __restrict__ bbv,
                const unsigned short* __restrict__ Qp16,
                const unsigned short* __restrict__ Kp16,
                const unsigned short* __restrict__ Vb16, const float* __restrict__ h,
                float* __restrict__ x, float* __restrict__ stat, int N, int EDG)
{
    __shared__ unsigned short WeB[128 * 128];  // 32 KB (d,k): byte d*256 + ((2k)^((d&7)<<4))
    __shared__ unsigned short WbB[16 * 128];   // 4 KB; reused as stats scratch at end
    __shared__ float scw[4][16][8];            // per-wave score redistribution
    __shared__ int   srw[4][16];               // per-wave src ids

    const int t = threadIdx.x;
    #pragma unroll
    for (int i = 0; i < 16; ++i) {
        const int idx4 = i * 256 + t;
        const int d = idx4 >> 5, k0 = (idx4 & 31) * 4;
        const float4 wv = *(const float4*)&We[d * 128 + k0];
        bf16x4 p;
        p[0] = (short)f2bf(wv.x); p[1] = (short)f2bf(wv.y);
        p[2] = (short)f2bf(wv.z); p[3] = (short)f2bf(wv.w);
        *(bf16x4*)((char*)WeB + d * 256 + ((2 * k0) ^ ((d & 7) << 4))) = p;
    }
    #pragma unroll
    for (int i = 0; i < 8; ++i) {
        const int idx = i * 256 + t;
        const int r = idx >> 7, k = idx & 127;
        const unsigned short v = (r < 8) ? f2bf(Wb[r * 128 + k]) : (unsigned short)0;
        *(unsigned short*)((char*)WbB + r * 256 + ((2 * k) ^ ((r & 7) << 4))) = v;
    }
    __syncthreads();                            // WeB/WbB ready; read-only in loop

    const int l = t & 63, w = t >> 6;
    const int eloc = l & 15;                    // edge slot (QK phase) / dim group vq (PV)
    const int g4 = l >> 4;                      // k-octet (QK) / edge stream ve (PV)
    const int kb_l = g4 * 16;
    const int hpv = eloc >> 1;                  // PV: head owning dims 8*eloc..+7

    float sA8[8], sQ8[8];
    #pragma unroll
    for (int j = 0; j < 8; ++j) { sA8[j] = 0.f; sQ8[j] = 0.f; }

    const int GW = gridDim.x * 4;
    for (int node = blockIdx.x * 4 + w; node < N; node += GW) {
        const int beg = offs[node], end = offs[node + 1];

        // Q (permuted bf16): 4x uint4, lane's contiguous 32 ushorts
        uint4 qu[4];
        {
            const unsigned short* qp = Qp16 + (size_t)node * 128 + g4 * 32;
            #pragma unroll
            for (int i = 0; i < 4; ++i) qu[i] = *(const uint4*)(qp + i * 8);
        }

        float pv8[8];
        #pragma unroll
        for (int j = 0; j < 8; ++j) pv8[j] = 0.f;
        float zz = 0.f;

        for (int base = beg; base < end; base += 16) {
            const int cnt = min(16, end - base);
            const int ii = min(base + eloc, EDG - 1);
            const int2 se = elist[ii];

            // ---- per-lane eattr B-fragment: load + immediate bf16 convert --
            bf16x8 frv[4];
            {
                const float* ep = eattr + (size_t)se.y * 128 + g4 * 8;
                #pragma unroll
                for (int ks = 0; ks < 4; ++ks) {
                    const float4 a0 = *(const float4*)(ep + ks * 32);
                    const float4 a1 = *(const float4*)(ep + ks * 32 + 4);
                    union { unsigned u[4]; bf16x8 v; } fr;
                    fr.u[0] = cvtpk(a0.x, a0.y);
                    fr.u[1] = cvtpk(a0.z, a0.w);
                    fr.u[2] = cvtpk(a1.x, a1.y);
                    fr.u[3] = cvtpk(a1.z, a1.w);
                    frv[ks] = fr.v;
                }
            }
            // K (permuted bf16): 4x uint4 contiguous per lane
            uint4 ku[4];
            {
                const unsigned short* kp = Kp16 + (size_t)se.x * 128 + g4 * 32;
                #pragma unroll
                for (int i = 0; i < 4; ++i) ku[i] = *(const uint4*)(kp + i * 8);
            }

            // ---- MFMA: 8 head tiles + 1 bias tile, K=128, single pass ----
            f32x4 acc[8], accb;
            #pragma unroll
            for (int hh = 0; hh < 8; ++hh) acc[hh] = (f32x4){0.f, 0.f, 0.f, 0.f};
            accb = (f32x4){0.f, 0.f, 0.f, 0.f};
            #pragma unroll
            for (int ks = 0; ks < 4; ++ks) {
                const int kb = ks * 64 + kb_l;
                const bf16x8 abf = *(const bf16x8*)((char*)WbB + eloc * 256 + (kb ^ ((eloc & 7) << 4)));
                accb = __builtin_amdgcn_mfma_f32_16x16x32_bf16(abf, frv[ks], accb, 0, 0, 0);
                #pragma unroll
                for (int hh = 0; hh < 8; ++hh) {
                    const int ar = hh * 16 + eloc;
                    const bf16x8 af = *(const bf16x8*)((char*)WeB + ar * 256 + (kb ^ ((ar & 7) << 4)));
                    acc[hh] = __builtin_amdgcn_mfma_f32_16x16x32_bf16(af, frv[ks], acc[hh], 0, 0, 0);
                }
            }

            // ---- score epilogue: bf16 K*Q (permuted regs) vs acc, reduce --
            float scv[8];
            #pragma unroll
            for (int hh = 0; hh < 8; ++hh) {
                const uint4 kv = ku[hh >> 1];
                const uint4 qv = qu[hh >> 1];
                const unsigned ka = (hh & 1) ? kv.z : kv.x;
                const unsigned kc2 = (hh & 1) ? kv.w : kv.y;
                const unsigned qa = (hh & 1) ? qv.z : qv.x;
                const unsigned qc2 = (hh & 1) ? qv.w : qv.y;
                float m = acc[hh][0] * (bflo(ka)  * bflo(qa))
                        + acc[hh][1] * (bfhi(ka)  * bfhi(qa))
                        + acc[hh][2] * (bflo(kc2) * bflo(qc2))
                        + acc[hh][3] * (bfhi(kc2) * bfhi(qc2));
                m += __shfl_xor(m, 16);
                m += __shfl_xor(m, 32);
                const float eb = __shfl(accb[hh & 3], ((hh >> 2) << 4) | eloc);
                float sc = m * 0.25f + eb + bbv[hh];
                sc = expf(fminf(fmaxf(sc, -5.f), 5.f));
                scv[hh] = (eloc < cnt) ? sc : 0.f;   // mask chunk tail
            }
            if (l < 16) {
                float4 s0 = {scv[0], scv[1], scv[2], scv[3]};
                float4 s1 = {scv[4], scv[5], scv[6], scv[7]};
                *(float4*)&scw[w][l][0] = s0;
                *(float4*)&scw[w][l][4] = s1;
                srw[w][l] = se.x;
            }
            asm volatile("s_waitcnt lgkmcnt(0)" ::: "memory");
            __builtin_amdgcn_sched_barrier(0);

            // ---- PV: quarter-wave per edge; lane owns dims 8*eloc..+7 ----
            for (int e = g4; e < cnt; e += 4) {
                const int   s0 = srw[w][e];
                const float c0 = scw[w][e][hpv];
                const uint4 u = *(const uint4*)(Vb16 + (size_t)s0 * 128 + eloc * 8);
                pv8[0] += bflo(u.x) * c0; pv8[1] += bfhi(u.x) * c0;
                pv8[2] += bflo(u.y) * c0; pv8[3] += bfhi(u.y) * c0;
                pv8[4] += bflo(u.z) * c0; pv8[5] += bfhi(u.z) * c0;
                pv8[6] += bflo(u.w) * c0; pv8[7] += bfhi(u.w) * c0;
                zz += c0;
            }
        }

        // merge edge streams (g4 groups), write x row from stream 0
        #pragma unroll
        for (int j = 0; j < 8; ++j) {
            pv8[j] += __shfl_xor(pv8[j], 16);
            pv8[j] += __shfl_xor(pv8[j], 32);
        }
        zz += __shfl_xor(zz, 16);
        zz += __shfl_xor(zz, 32);
        if (g4 == 0) {
            const float inv = 1.f / (zz + 1e-6f);
            const float4 h0 = *(const float4*)&h[(size_t)node * 128 + eloc * 8];
            const float4 h1 = *(const float4*)&h[(size_t)node * 128 + eloc * 8 + 4];
            float4 x0, x1;
            x0.x = h0.x + pv8[0] * inv; x0.y = h0.y + pv8[1] * inv;
            x0.z = h0.z + pv8[2] * inv; x0.w = h0.w + pv8[3] * inv;
            x1.x = h1.x + pv8[4] * inv; x1.y = h1.y + pv8[5] * inv;
            x1.z = h1.z + pv8[6] * inv; x1.w = h1.w + pv8[7] * inv;
            *(float4*)&x[(size_t)node * 128 + eloc * 8]     = x0;
            *(float4*)&x[(size_t)node * 128 + eloc * 8 + 4] = x1;
            sA8[0] += x0.x; sA8[1] += x0.y; sA8[2] += x0.z; sA8[3] += x0.w;
            sA8[4] += x1.x; sA8[5] += x1.y; sA8[6] += x1.z; sA8[7] += x1.w;
            sQ8[0] += x0.x * x0.x; sQ8[1] += x0.y * x0.y;
            sQ8[2] += x0.z * x0.z; sQ8[3] += x0.w * x0.w;
            sQ8[4] += x1.x * x1.x; sQ8[5] += x1.y * x1.y;
            sQ8[6] += x1.z * x1.z; sQ8[7] += x1.w * x1.w;
        }
    }

    // ---- stats: reuse WbB as scratch (all waves past the loop) ----
    __syncthreads();
    float* wbF = (float*)WbB;                   // 1024 floats
    if (g4 == 0) {
        #pragma unroll
        for (int j = 0; j < 8; ++j) {
            wbF[w * 256 + eloc * 8 + j]       = sA8[j];
            wbF[w * 256 + 128 + eloc * 8 + j] = sQ8[j];
        }
    }
    __syncthreads();
    if (t < 128) {
        float s = 0.f, sq2 = 0.f;
        #pragma unroll
        for (int wi = 0; wi < 4; ++wi) {
            s   += wbF[wi * 256 + t];
            sq2 += wbF[wi * 256 + 128 + t];
        }
        atomicAdd(&stat[t], s);
        atomicAdd(&stat[128 + t], sq2);
    }
}

// ---------------------------------------------------------- BN params ------
__global__ void bn_params(const float* __restrict__ sum, const float* __restrict__ sumsq,
                          const float* __restrict__ gamma, const float* __restrict__ beta,
                          float* __restrict__ a, float* __restrict__ b, float invn)
{
    const int c = threadIdx.x;
    const float mean = sum[c] * invn;
    const float var  = sumsq[c] * invn - mean * mean;
    const float sc   = gamma[c] * rsqrtf(var + 1e-5f);
    a[c] = sc;
    b[c] = beta[c] - mean * sc;
}

// ---------------------------------------------------------------- FFN ------
__global__ __launch_bounds__(128)
void ffn_kernel(const float* __restrict__ x, const float* __restrict__ W1,
                const float* __restrict__ b1, const float* __restrict__ W2,
                const float* __restrict__ b2, const float* __restrict__ par,
                float* __restrict__ zb, float* __restrict__ stat2)
{
    __shared__ float xnl[16 * 128];
    __shared__ float hidl[16 * 256];
    const int t  = threadIdx.x;
    const int n0 = blockIdx.x * 16;

    const float4* xg4 = (const float4*)(x + (size_t)n0 * 128);
    const float4* a4  = (const float4*)par;
    const float4* bv4 = (const float4*)(par + 128);
    float4* xnl4 = (float4*)xnl;
    #pragma unroll
    for (int i = 0; i < 4; ++i) {
        const int idx = i * 128 + t;
        const float4 xv = xg4[idx];
        const float4 av = a4[idx & 31], bv = bv4[idx & 31];
        float4 r;
        r.x = xv.x * av.x + bv.x; r.y = xv.y * av.y + bv.y;
        r.z = xv.z * av.z + bv.z; r.w = xv.w * av.w + bv.w;
        xnl4[idx] = r;
    }
    __syncthreads();

    float acc0[16], acc1[16];
    #pragma unroll
    for (int n = 0; n < 16; ++n) { acc0[n] = 0.f; acc1[n] = 0.f; }
    const float* w0p = W1 + (size_t)t * 128;
    const float* w1p = W1 + (size_t)(t + 128) * 128;
    for (int kc = 0; kc < 32; ++kc) {
        const float4 w0 = *(const float4*)(w0p + kc * 4);
        const float4 w1 = *(const float4*)(w1p + kc * 4);
        #pragma unroll
        for (int n = 0; n < 16; ++n) {
            const float4 xv = *(const float4*)&xnl[n * 128 + kc * 4];
            acc0[n] += w0.x * xv.x + w0.y * xv.y + w0.z * xv.z + w0.w * xv.w;
            acc1[n] += w1.x * xv.x + w1.y * xv.y + w1.z * xv.z + w1.w * xv.w;
        }
    }
    const float bi0 = b1[t], bi1 = b1[t + 128];
    #pragma unroll
    for (int n = 0; n < 16; ++n) {
        hidl[n * 256 + t]       = fmaxf(acc0[n] + bi0, 0.f);
        hidl[n * 256 + 128 + t] = fmaxf(acc1[n] + bi1, 0.f);
    }
    __syncthreads();

    float acc2[16];
    #pragma unroll
    for (int n = 0; n < 16; ++n) acc2[n] = 0.f;
    const float* w2p = W2 + (size_t)t * 256;
    for (int kc = 0; kc < 64; ++kc) {
        const float4 w = *(const float4*)(w2p + kc * 4);
        #pragma unroll
        for (int n = 0; n < 16; ++n) {
            const float4 hv = *(const float4*)&hidl[n * 256 + kc * 4];
            acc2[n] += w.x * hv.x + w.y * hv.y + w.z * hv.z + w.w * hv.w;
        }
    }
    const float bi2 = b2[t];
    float s = 0.f, sq = 0.f;
    float* zo = zb + (size_t)n0 * 128 + t;
    #pragma unroll
    for (int n = 0; n < 16; ++n) {
        const float z = xnl[n * 128 + t] + acc2[n] + bi2;
        zo[(size_t)n * 128] = z;
        s += z; sq += z * z;
    }
    atomicAdd(&stat2[t], s);
    atomicAdd(&stat2[128 + t], sq);
}

// ---------------------------------------------------------- final BN -------
__global__ void final_bn(const float4* __restrict__ zb, const float* __restrict__ pa,
                         const float* __restrict__ pb, float4* __restrict__ out, int total4)
{
    const float4* a4 = (const float4*)pa;
    const float4* b4 = (const float4*)pb;
    const int stride = gridDim.x * blockDim.x;
    for (int i = blockIdx.x * blockDim.x + threadIdx.x; i < total4; i += stride) {
        const float4 z = zb[i];
        const float4 a = a4[i & 31], b = b4[i & 31];
        float4 r;
        r.x = z.x * a.x + b.x; r.y = z.y * a.y + b.y;
        r.z = z.z * a.z + b.z; r.w = z.w * a.w + b.w;
        out[i] = r;
    }
}

// ---------------------------------------------------------------------------
extern "C" void kernel_launch(void* const* d_in, const int* in_sizes, int n_in,
                              void* d_out, int out_size, void* d_ws, size_t ws_size,
                              hipStream_t stream)
{
    const float* h   = (const float*)d_in[0];
    const int*   ei  = (const int*)  d_in[1];
    const float* ea  = (const float*)d_in[2];
    const float* Wq  = (const float*)d_in[3];
    const float* Wk  = (const float*)d_in[4];
    const float* Wv  = (const float*)d_in[5];
    const float* We  = (const float*)d_in[6];
    const float* Wb  = (const float*)d_in[7];
    const float* bbv = (const float*)d_in[8];
    const float* g1  = (const float*)d_in[9];
    const float* be1 = (const float*)d_in[10];
    const float* W1  = (const float*)d_in[11];
    const float* b1  = (const float*)d_in[12];
    const float* W2  = (const float*)d_in[13];
    const float* b2  = (const float*)d_in[14];
    const float* g2  = (const float*)d_in[15];
    const float* be2 = (const float*)d_in[16];
    float* out = (float*)d_out;

    const int N   = in_sizes[0] / 128;
    const int EDG = in_sizes[1] / 2;
    const int NB  = (N + 1023) / 1024;
    const size_t nd = (size_t)N * 128;
    auto al8 = [](size_t v){ return (v + 7) & ~(size_t)7; };

    float* ws = (float*)d_ws;
    const size_t Xo  = 0;                            // x (attn output, fp32)
    const size_t Zo  = nd;                           // ffn z output (fp32)
    const size_t Q16 = 2 * nd;                       // Qp16 (nd ushorts = nd/2 f32)
    const size_t K16 = 2 * nd + nd / 2;              // Kp16
    const size_t V16 = 3 * nd;                       // Vb16
    const size_t ELo = 3 * nd + nd / 2;              // elist (EDG int2)
    const size_t OFo = ELo + (size_t)EDG * 2;        // offs (N+1 int)
    const size_t CUo = al8(OFo + (size_t)N + 8);     // counts (N int)
    const size_t BSo = al8(CUo + (size_t)N);         // block sums (NB int)
    const size_t BBo = al8(BSo + (size_t)NB);        // block bases (NB int)
    const size_t STo = al8(BBo + (size_t)NB);        // stats: 512 f32
    const size_t PAR = STo + 512;                    // bn params: 512 f32

    int*  cnt   = (int*)(ws + CUo);
    int*  offs  = (int*)(ws + OFo);
    int*  bsum  = (int*)(ws + BSo);
    int*  bbase = (int*)(ws + BBo);
    int2* elist = (int2*)(ws + ELo);
    unsigned short* qp16 = (unsigned short*)(ws + Q16);
    unsigned short* kp16 = (unsigned short*)(ws + K16);
    unsigned short* vb16 = (unsigned short*)(ws + V16);

    hipMemsetAsync(cnt, 0, (size_t)N * sizeof(int), stream);
    hipMemsetAsync(ws + STo, 0, 512 * sizeof(float), stream);

    qkv_kernel<<<N / 16, 128, 0, stream>>>(h, Wq, Wk, Wv, qp16, kp16, vb16);

    hist_kernel<<<1024, 256, 0, stream>>>(ei, cnt, EDG);
    scan_a<<<NB, 1024, 0, stream>>>(cnt, bsum, N);
    scan_b<<<1, 64, 0, stream>>>(bsum, bbase, offs, NB, N);
    scan_c<<<NB, 1024, 0, stream>>>(cnt, bbase, offs, N);
    scatter_kernel<<<1024, 256, 0, stream>>>(ei, offs, cnt, elist, EDG);

    fused_attn<<<1024, 256, 0, stream>>>(ea, elist, offs, We, Wb, bbv,
                                         qp16, kp16, vb16, h,
                                         ws + Xo, ws + STo, N, EDG);

    bn_params<<<1, 128, 0, stream>>>(ws + STo, ws + STo + 128, g1, be1,
                                     ws + PAR, ws + PAR + 128, 1.0f / (float)N);
    ffn_kernel<<<N / 16, 128, 0, stream>>>(ws + Xo, W1, b1, W2, b2, ws + PAR,
                                           ws + Zo, ws + STo + 256);
    bn_params<<<1, 128, 0, stream>>>(ws + STo + 256, ws + STo + 384, g2, be2,
                                     ws + PAR + 256, ws + PAR + 384, 1.0f / (float)N);
    final_bn<<<1024, 256, 0, stream>>>((const float4*)(ws + Zo), ws + PAR + 256,
                                       ws + PAR + 384, (float4*)out, N * 32);
}

// Round 13
// 1003.057 us; speedup vs baseline: 1.2010x; 1.2010x over previous
//
#include <hip/hip_runtime.h>
#include <math.h>

typedef __attribute__((ext_vector_type(8))) short bf16x8;
typedef __attribute__((ext_vector_type(4))) short bf16x4;
typedef __attribute__((ext_vector_type(4))) float f32x4;

static __device__ __forceinline__ unsigned short f2bf(float x){
    union{float f; unsigned u;} v; v.f = x;
    unsigned r = v.u + 0x7fffu + ((v.u >> 16) & 1u);
    return (unsigned short)(r >> 16);
}
static __device__ __forceinline__ unsigned cvtpk(float lo, float hi){
    unsigned r;
    asm("v_cvt_pk_bf16_f32 %0, %1, %2" : "=v"(r) : "v"(lo), "v"(hi));
    return r;
}
static __device__ __forceinline__ float bflo(unsigned u){
    union{unsigned x; float f;} v; v.x = u << 16; return v.f;
}

// --------------------------------------------- one-shot weight conversion --
// WeS/WbS: bf16 PRE-SWIZZLED (byte pos = row*256 + ((2k)^((row&7)<<4))).
// Wq/Wk/Wv/W1/W2: plain bf16 row-major.
__global__ __launch_bounds__(256)
void convert_w(const float* __restrict__ We, const float* __restrict__ Wb,
               const float* __restrict__ Wq, const float* __restrict__ Wk,
               const float* __restrict__ Wv, const float* __restrict__ W1,
               const float* __restrict__ W2,
               unsigned short* __restrict__ WeS, unsigned short* __restrict__ WbS,
               unsigned short* __restrict__ Wqb, unsigned short* __restrict__ Wkb,
               unsigned short* __restrict__ Wvb, unsigned short* __restrict__ W1b,
               unsigned short* __restrict__ W2b)
{
    const int t = blockIdx.x * 256 + threadIdx.x;
    if (t < 16384) {
        const int d = t >> 7, k = t & 127;
        const int pb = d * 256 + ((2 * k) ^ ((d & 7) << 4));
        *(unsigned short*)((char*)WeS + pb) = f2bf(We[t]);
        Wqb[t] = f2bf(Wq[t]); Wkb[t] = f2bf(Wk[t]); Wvb[t] = f2bf(Wv[t]);
    }
    if (t < 2048) {
        const int r = t >> 7, k = t & 127;
        const int pb = r * 256 + ((2 * k) ^ ((r & 7) << 4));
        *(unsigned short*)((char*)WbS + pb) = (r < 8) ? f2bf(Wb[r * 128 + k])
                                                      : (unsigned short)0;
    }
    if (t < 32768) { W1b[t] = f2bf(W1[t]); W2b[t] = f2bf(W2[t]); }
}

// ------------------------------------------------------- QKV via MFMA ------
// 64 nodes/block, 4 waves. h staged bf16-swizzled in LDS. Per matrix:
// wave w owns output dims [w*32, w*32+32) (2 B-tiles) x 4 node tiles.
// D layout: col=lane&15 (weight row d), row=(lane>>4)*4+r (node).
__global__ __launch_bounds__(256, 3)
void qkv_mfma(const float* __restrict__ h, const unsigned short* __restrict__ Wqb,
              const unsigned short* __restrict__ Wkb, const unsigned short* __restrict__ Wvb,
              float* __restrict__ Qb, float* __restrict__ Kb, float* __restrict__ Vb, int N)
{
    __shared__ unsigned short hB[64 * 128];  // 16 KB swizzled
    const int t = threadIdx.x;
    const int n0 = blockIdx.x * 64;

    #pragma unroll
    for (int i = 0; i < 4; ++i) {
        const int idx8 = i * 256 + t;        // 0..1023 chunks of 8
        const int r = idx8 >> 4, k0 = (idx8 & 15) * 8;
        const int n = n0 + r;
        float4 a0 = {0,0,0,0}, a1 = {0,0,0,0};
        if (n < N) {
            a0 = *(const float4*)&h[(size_t)n * 128 + k0];
            a1 = *(const float4*)&h[(size_t)n * 128 + k0 + 4];
        }
        union { unsigned u[4]; bf16x8 v; } fr;
        fr.u[0] = cvtpk(a0.x, a0.y); fr.u[1] = cvtpk(a0.z, a0.w);
        fr.u[2] = cvtpk(a1.x, a1.y); fr.u[3] = cvtpk(a1.z, a1.w);
        *(bf16x8*)((char*)hB + r * 256 + ((2 * k0) ^ ((r & 7) << 4))) = fr.v;
    }
    __syncthreads();

    const int l = t & 63, w = t >> 6;
    const int eloc = l & 15, g4 = l >> 4;
    const int kb_l = g4 * 16;

    #pragma unroll
    for (int m = 0; m < 3; ++m) {
        const unsigned short* Wm = (m == 0 ? Wqb : (m == 1 ? Wkb : Wvb));
        float* Om = (m == 0 ? Qb : (m == 1 ? Kb : Vb));
        f32x4 acc[4][2];
        #pragma unroll
        for (int tt = 0; tt < 4; ++tt)
            #pragma unroll
            for (int u = 0; u < 2; ++u) acc[tt][u] = (f32x4){0.f,0.f,0.f,0.f};
        #pragma unroll
        for (int ks = 0; ks < 4; ++ks) {
            const int kb = ks * 64 + kb_l;
            bf16x8 a[4];
            #pragma unroll
            for (int tt = 0; tt < 4; ++tt) {
                const int ar = tt * 16 + eloc;
                a[tt] = *(const bf16x8*)((char*)hB + ar * 256 + (kb ^ ((ar & 7) << 4)));
            }
            #pragma unroll
            for (int u = 0; u < 2; ++u) {
                const int d = w * 32 + u * 16 + eloc;
                const bf16x8 b = *(const bf16x8*)(Wm + d * 128 + ks * 32 + g4 * 8);
                #pragma unroll
                for (int tt = 0; tt < 4; ++tt)
                    acc[tt][u] = __builtin_amdgcn_mfma_f32_16x16x32_bf16(a[tt], b, acc[tt][u], 0, 0, 0);
            }
        }
        #pragma unroll
        for (int tt = 0; tt < 4; ++tt)
            #pragma unroll
            for (int u = 0; u < 2; ++u) {
                const int dcol = w * 32 + u * 16 + eloc;
                #pragma unroll
                for (int r = 0; r < 4; ++r) {
                    const int n = n0 + tt * 16 + g4 * 4 + r;
                    if (n < N) Om[(size_t)n * 128 + dcol] = acc[tt][u][r];
                }
            }
        __syncthreads();   // hB reused read-only; cheap resync between matrices
    }
}

// ------------------------------------------------------------- CSR build ---
__global__ void hist_kernel(const int* __restrict__ ei, int* __restrict__ cnt, int EDG)
{
    const int stride = gridDim.x * blockDim.x;
    for (int e = blockIdx.x * blockDim.x + threadIdx.x; e < EDG; e += stride)
        atomicAdd(&cnt[ei[EDG + e]], 1);
}

__global__ __launch_bounds__(1024)
void scan_a(const int* __restrict__ cnt, int* __restrict__ bsum, int n)
{
    __shared__ int tmp[1024];
    const int t = threadIdx.x;
    const int i = blockIdx.x * 1024 + t;
    tmp[t] = (i < n) ? cnt[i] : 0;
    __syncthreads();
    for (int d = 512; d > 0; d >>= 1) {
        if (t < d) tmp[t] += tmp[t + d];
        __syncthreads();
    }
    if (t == 0) bsum[blockIdx.x] = tmp[0];
}

__global__ void scan_b(const int* __restrict__ bsum, int* __restrict__ bbase,
                       int* __restrict__ offs, int nb, int n)
{
    if (threadIdx.x == 0) {
        int run = 0;
        for (int b = 0; b < nb; ++b) { bbase[b] = run; run += bsum[b]; }
        offs[n] = run;
    }
}

__global__ __launch_bounds__(1024)
void scan_c(const int* __restrict__ cnt, const int* __restrict__ bbase,
            int* __restrict__ offs, int n)
{
    __shared__ int tmp[1024];
    const int t = threadIdx.x;
    const int i = blockIdx.x * 1024 + t;
    const int v = (i < n) ? cnt[i] : 0;
    tmp[t] = v;
    __syncthreads();
    for (int d = 1; d < 1024; d <<= 1) {
        const int a = (t >= d) ? tmp[t - d] : 0;
        __syncthreads();
        tmp[t] += a;
        __syncthreads();
    }
    if (i < n) offs[i] = bbase[blockIdx.x] + tmp[t] - v;
}

__global__ void scatter_kernel(const int* __restrict__ ei, const int* __restrict__ offs,
                               int* __restrict__ cnt, int2* __restrict__ elist, int EDG)
{
    const int stride = gridDim.x * blockDim.x;
    for (int e = blockIdx.x * blockDim.x + threadIdx.x; e < EDG; e += stride) {
        const int d = ei[EDG + e];
        const int p = atomicSub(&cnt[d], 1) - 1;
        int2 v; v.x = ei[e]; v.y = e;
        elist[offs[d] + p] = v;
    }
}

// --------------------------------------- fused edge-score + gather (MFMA) --
// ROUND-6 PROVEN STRUCTURE (489 us): fp32 Q/K/V, single-pass 8-head MFMA,
// half-split float4 PV, grid 768, (256,3). Only change: We/Wb staged by
// plain uint4 copy from pre-swizzled bf16 globals.
__global__ __launch_bounds__(256, 3)
void fused_attn(const float* __restrict__ eattr, const int2* __restrict__ elist,
                const int* __restrict__ offs,
                const unsigned short* __restrict__ WeS, const unsigned short* __restrict__ WbS,
                const float* __restrict__ bbv,
                const float* __restrict__ Qb, const float* __restrict__ Kb,
                const float* __restrict__ Vb, const float* __restrict__ h,
                float* __restrict__ x, float* __restrict__ stat, int N, int EDG)
{
    __shared__ unsigned short WeB[128 * 128];  // 32 KB pre-swizzled
    __shared__ unsigned short WbB[16 * 128];   // 4 KB
    __shared__ float scw[4][16][8];
    __shared__ int   srw[4][16];
    __shared__ float ssl[4][128];
    __shared__ float sql[4][128];

    const int t = threadIdx.x;
    {
        const uint4* wesrc = (const uint4*)WeS;
        uint4* wedst = (uint4*)WeB;
        #pragma unroll
        for (int i = 0; i < 8; ++i) wedst[i * 256 + t] = wesrc[i * 256 + t];
        if (t < 256) ((uint4*)WbB)[t] = ((const uint4*)WbS)[t];
    }
    __syncthreads();

    const int l = t & 63, w = t >> 6;
    const int eloc = l & 15, g4 = l >> 4;
    const int half = l >> 5, q = l & 31;
    const int hq = q >> 2;
    const int kb_l = g4 * 16;
    float bb[8];
    #pragma unroll
    for (int hh = 0; hh < 8; ++hh) bb[hh] = bbv[hh];

    float4 sA = {0.f, 0.f, 0.f, 0.f}, sQ2 = {0.f, 0.f, 0.f, 0.f};
    const int GW = gridDim.x * 4;
    for (int node = blockIdx.x * 4 + w; node < N; node += GW) {
        const int beg = offs[node], end = offs[node + 1];

        const float* qrow = Qb + (size_t)node * 128 + g4 * 4;
        float4 qv[8];
        #pragma unroll
        for (int hh = 0; hh < 8; ++hh) qv[hh] = *(const float4*)(qrow + hh * 16);

        float4 pv = {0.f, 0.f, 0.f, 0.f};
        float zz = 0.f;

        for (int base = beg; base < end; base += 16) {
            const int cnt = min(16, end - base);
            const int ii = min(base + eloc, EDG - 1);
            const int2 se = elist[ii];

            bf16x8 frv[4];
            {
                const float* ep = eattr + (size_t)se.y * 128 + g4 * 8;
                #pragma unroll
                for (int ks = 0; ks < 4; ++ks) {
                    const float4 a0 = *(const float4*)(ep + ks * 32);
                    const float4 a1 = *(const float4*)(ep + ks * 32 + 4);
                    union { unsigned u[4]; bf16x8 v; } fr;
                    fr.u[0] = cvtpk(a0.x, a0.y);
                    fr.u[1] = cvtpk(a0.z, a0.w);
                    fr.u[2] = cvtpk(a1.x, a1.y);
                    fr.u[3] = cvtpk(a1.z, a1.w);
                    frv[ks] = fr.v;
                }
            }
            const float* kr = Kb + (size_t)se.x * 128 + g4 * 4;

            f32x4 acc[8], accb;
            #pragma unroll
            for (int hh = 0; hh < 8; ++hh) acc[hh] = (f32x4){0.f, 0.f, 0.f, 0.f};
            accb = (f32x4){0.f, 0.f, 0.f, 0.f};
            #pragma unroll
            for (int ks = 0; ks < 4; ++ks) {
                const int kb = ks * 64 + kb_l;
                const bf16x8 abf = *(const bf16x8*)((char*)WbB + eloc * 256 + (kb ^ ((eloc & 7) << 4)));
                accb = __builtin_amdgcn_mfma_f32_16x16x32_bf16(abf, frv[ks], accb, 0, 0, 0);
                #pragma unroll
                for (int hh = 0; hh < 8; ++hh) {
                    const int ar = hh * 16 + eloc;
                    const bf16x8 af = *(const bf16x8*)((char*)WeB + ar * 256 + (kb ^ ((ar & 7) << 4)));
                    acc[hh] = __builtin_amdgcn_mfma_f32_16x16x32_bf16(af, frv[ks], acc[hh], 0, 0, 0);
                }
            }

            float scv[8];
            #pragma unroll
            for (int hh = 0; hh < 8; ++hh) {
                const float4 kk = *(const float4*)(kr + hh * 16);
                const float4 qq = qv[hh];
                float m = acc[hh][0] * (kk.x * qq.x) + acc[hh][1] * (kk.y * qq.y)
                        + acc[hh][2] * (kk.z * qq.z) + acc[hh][3] * (kk.w * qq.w);
                m += __shfl_xor(m, 16);
                m += __shfl_xor(m, 32);
                const float eb = __shfl(accb[hh & 3], ((hh >> 2) << 4) | eloc);
                float sc = m * 0.25f + eb + bb[hh];
                sc = expf(fminf(fmaxf(sc, -5.f), 5.f));
                scv[hh] = (eloc < cnt) ? sc : 0.f;
            }
            if (l < 16) {
                float4 s0 = {scv[0], scv[1], scv[2], scv[3]};
                float4 s1 = {scv[4], scv[5], scv[6], scv[7]};
                *(float4*)&scw[w][l][0] = s0;
                *(float4*)&scw[w][l][4] = s1;
                srw[w][l] = se.x;
            }
            asm volatile("s_waitcnt lgkmcnt(0)" ::: "memory");
            __builtin_amdgcn_sched_barrier(0);

            int e = half;
            for (; e + 2 < cnt; e += 4) {
                const int   s0 = srw[w][e],     s1 = srw[w][e + 2];
                const float c0 = scw[w][e][hq], c1 = scw[w][e + 2][hq];
                const float4 v0 = *(const float4*)&Vb[(size_t)s0 * 128 + 4 * q];
                const float4 v1 = *(const float4*)&Vb[(size_t)s1 * 128 + 4 * q];
                pv.x += v0.x * c0 + v1.x * c1;
                pv.y += v0.y * c0 + v1.y * c1;
                pv.z += v0.z * c0 + v1.z * c1;
                pv.w += v0.w * c0 + v1.w * c1;
                zz += c0 + c1;
            }
            for (; e < cnt; e += 2) {
                const int   s0 = srw[w][e];
                const float c0 = scw[w][e][hq];
                const float4 v0 = *(const float4*)&Vb[(size_t)s0 * 128 + 4 * q];
                pv.x += v0.x * c0; pv.y += v0.y * c0;
                pv.z += v0.z * c0; pv.w += v0.w * c0;
                zz += c0;
            }
        }

        pv.x += __shfl_xor(pv.x, 32); pv.y += __shfl_xor(pv.y, 32);
        pv.z += __shfl_xor(pv.z, 32); pv.w += __shfl_xor(pv.w, 32);
        zz   += __shfl_xor(zz, 32);
        if (half == 0) {
            const float inv = 1.f / (zz + 1e-6f);
            const float4 hv = *(const float4*)&h[(size_t)node * 128 + 4 * q];
            float4 xv;
            xv.x = hv.x + pv.x * inv; xv.y = hv.y + pv.y * inv;
            xv.z = hv.z + pv.z * inv; xv.w = hv.w + pv.w * inv;
            *(float4*)&x[(size_t)node * 128 + 4 * q] = xv;
            sA.x += xv.x; sA.y += xv.y; sA.z += xv.z; sA.w += xv.w;
            sQ2.x += xv.x * xv.x; sQ2.y += xv.y * xv.y;
            sQ2.z += xv.z * xv.z; sQ2.w += xv.w * xv.w;
        }
    }

    float4 zf = {0.f, 0.f, 0.f, 0.f};
    if (half == 0) {
        *(float4*)&ssl[w][4 * q] = sA;
        *(float4*)&sql[w][4 * q] = sQ2;
    } else {
        *(float4*)&ssl[w][4 * q] = zf;   // unused slots (q>=32 region not present)
    }
    __syncthreads();
    if (t < 128) {
        atomicAdd(&stat[t],       ssl[0][t] + ssl[1][t] + ssl[2][t] + ssl[3][t]);
        atomicAdd(&stat[128 + t], sql[0][t] + sql[1][t] + sql[2][t] + sql[3][t]);
    }
}

// ---------------------------------------------------------- BN params ------
__global__ void bn_params(const float* __restrict__ sum, const float* __restrict__ sumsq,
                          const float* __restrict__ gamma, const float* __restrict__ beta,
                          float* __restrict__ a, float* __restrict__ b, float invn)
{
    const int c = threadIdx.x;
    const float mean = sum[c] * invn;
    const float var  = sumsq[c] * invn - mean * mean;
    const float sc   = gamma[c] * rsqrtf(var + 1e-5f);
    a[c] = sc;
    b[c] = beta[c] - mean * sc;
}

// ------------------------------------------------------- FFN via MFMA ------
// 64 nodes/block, 4 waves. xn = BN1(x) staged bf16-swizzled; phase1
// hidden=relu(xn@W1^T+b1) -> hidB bf16; phase2 out=hid@W2^T+b2, z=xn+out,
// fused BN2 stats.
__global__ __launch_bounds__(256, 2)
void ffn_mfma(const float* __restrict__ x, const unsigned short* __restrict__ W1b,
              const float* __restrict__ b1, const unsigned short* __restrict__ W2b,
              const float* __restrict__ b2, const float* __restrict__ par,
              float* __restrict__ zb, float* __restrict__ stat2, int N)
{
    __shared__ unsigned short xnB[64 * 128];   // 16 KB swizzled (row stride 256 B)
    __shared__ unsigned short hidB[64 * 256];  // 32 KB swizzled (row stride 512 B)
    const int t = threadIdx.x;
    const int n0 = blockIdx.x * 64;
    const float4* a4  = (const float4*)par;
    const float4* bv4 = (const float4*)(par + 128);

    #pragma unroll
    for (int i = 0; i < 4; ++i) {
        const int idx8 = i * 256 + t;
        const int r = idx8 >> 4, k0 = (idx8 & 15) * 8;
        const int n = n0 + r;
        float4 v0 = {0,0,0,0}, v1 = {0,0,0,0};
        if (n < N) {
            const float4 x0 = *(const float4*)&x[(size_t)n * 128 + k0];
            const float4 x1 = *(const float4*)&x[(size_t)n * 128 + k0 + 4];
            const float4 aa0 = a4[k0 >> 2],       bb0 = bv4[k0 >> 2];
            const float4 aa1 = a4[(k0 >> 2) + 1], bb1 = bv4[(k0 >> 2) + 1];
            v0.x = x0.x * aa0.x + bb0.x; v0.y = x0.y * aa0.y + bb0.y;
            v0.z = x0.z * aa0.z + bb0.z; v0.w = x0.w * aa0.w + bb0.w;
            v1.x = x1.x * aa1.x + bb1.x; v1.y = x1.y * aa1.y + bb1.y;
            v1.z = x1.z * aa1.z + bb1.z; v1.w = x1.w * aa1.w + bb1.w;
        }
        union { unsigned u[4]; bf16x8 v; } fr;
        fr.u[0] = cvtpk(v0.x, v0.y); fr.u[1] = cvtpk(v0.z, v0.w);
        fr.u[2] = cvtpk(v1.x, v1.y); fr.u[3] = cvtpk(v1.z, v1.w);
        *(bf16x8*)((char*)xnB + r * 256 + ((2 * k0) ^ ((r & 7) << 4))) = fr.v;
    }
    __syncthreads();

    const int l = t & 63, w = t >> 6;
    const int eloc = l & 15, g4 = l >> 4;
    const int kb_l = g4 * 16;

    // ---- phase 1: hidden = relu(xn @ W1^T + b1); wave w -> j in [w*64, +64)
    {
        f32x4 acc[4][4];
        #pragma unroll
        for (int tt = 0; tt < 4; ++tt)
            #pragma unroll
            for (int u = 0; u < 4; ++u) acc[tt][u] = (f32x4){0.f,0.f,0.f,0.f};
        #pragma unroll
        for (int ks = 0; ks < 4; ++ks) {
            const int kb = ks * 64 + kb_l;
            bf16x8 a[4];
            #pragma unroll
            for (int tt = 0; tt < 4; ++tt) {
                const int ar = tt * 16 + eloc;
                a[tt] = *(const bf16x8*)((char*)xnB + ar * 256 + (kb ^ ((ar & 7) << 4)));
            }
            #pragma unroll
            for (int u = 0; u < 4; ++u) {
                const int j = w * 64 + u * 16 + eloc;
                const bf16x8 b = *(const bf16x8*)(W1b + j * 128 + ks * 32 + g4 * 8);
                #pragma unroll
                for (int tt = 0; tt < 4; ++tt)
                    acc[tt][u] = __builtin_amdgcn_mfma_f32_16x16x32_bf16(a[tt], b, acc[tt][u], 0, 0, 0);
            }
        }
        #pragma unroll
        for (int u = 0; u < 4; ++u) {
            const int j = w * 64 + u * 16 + eloc;
            const float bj = b1[j];
            #pragma unroll
            for (int tt = 0; tt < 4; ++tt) {
                #pragma unroll
                for (int r = 0; r < 4; ++r) {
                    const int node = tt * 16 + g4 * 4 + r;
                    const float hv = fmaxf(acc[tt][u][r] + bj, 0.f);
                    *(unsigned short*)((char*)hidB + node * 512 + ((2 * j) ^ ((node & 7) << 4))) = f2bf(hv);
                }
            }
        }
    }
    __syncthreads();

    // ---- phase 2: out = hid @ W2^T + b2; z = xn + out; wave w -> c [w*32,+32)
    {
        f32x4 acc[4][2];
        #pragma unroll
        for (int tt = 0; tt < 4; ++tt)
            #pragma unroll
            for (int u = 0; u < 2; ++u) acc[tt][u] = (f32x4){0.f,0.f,0.f,0.f};
        #pragma unroll
        for (int ks = 0; ks < 8; ++ks) {
            const int kb = ks * 64 + kb_l;
            bf16x8 a[4];
            #pragma unroll
            for (int tt = 0; tt < 4; ++tt) {
                const int ar = tt * 16 + eloc;
                a[tt] = *(const bf16x8*)((char*)hidB + ar * 512 + (kb ^ ((ar & 7) << 4)));
            }
            #pragma unroll
            for (int u = 0; u < 2; ++u) {
                const int c = w * 32 + u * 16 + eloc;
                const bf16x8 b = *(const bf16x8*)(W2b + c * 256 + ks * 32 + g4 * 8);
                #pragma unroll
                for (int tt = 0; tt < 4; ++tt)
                    acc[tt][u] = __builtin_amdgcn_mfma_f32_16x16x32_bf16(a[tt], b, acc[tt][u], 0, 0, 0);
            }
        }
        #pragma unroll
        for (int u = 0; u < 2; ++u) {
            const int c = w * 32 + u * 16 + eloc;
            const float bc = b2[c];
            float s = 0.f, sq = 0.f;
            #pragma unroll
            for (int tt = 0; tt < 4; ++tt) {
                #pragma unroll
                for (int r = 0; r < 4; ++r) {
                    const int node = tt * 16 + g4 * 4 + r;
                    const int n = n0 + node;
                    const unsigned short xu = *(const unsigned short*)
                        ((char*)xnB + node * 256 + ((2 * c) ^ ((node & 7) << 4)));
                    const float z = bflo(xu) + acc[tt][u][r] + bc;
                    if (n < N) {
                        zb[(size_t)n * 128 + c] = z;
                        s += z; sq += z * z;
                    }
                }
            }
            atomicAdd(&stat2[c], s);
            atomicAdd(&stat2[128 + c], sq);
        }
    }
}

// ---------------------------------------------------------- final BN -------
__global__ void final_bn(const float4* __restrict__ zb, const float* __restrict__ pa,
                         const float* __restrict__ pb, float4* __restrict__ out, int total4)
{
    const float4* a4 = (const float4*)pa;
    const float4* b4 = (const float4*)pb;
    const int stride = gridDim.x * blockDim.x;
    for (int i = blockIdx.x * blockDim.x + threadIdx.x; i < total4; i += stride) {
        const float4 z = zb[i];
        const float4 a = a4[i & 31], b = b4[i & 31];
        float4 r;
        r.x = z.x * a.x + b.x; r.y = z.y * a.y + b.y;
        r.z = z.z * a.z + b.z; r.w = z.w * a.w + b.w;
        out[i] = r;
    }
}

// ---------------------------------------------------------------------------
extern "C" void kernel_launch(void* const* d_in, const int* in_sizes, int n_in,
                              void* d_out, int out_size, void* d_ws, size_t ws_size,
                              hipStream_t stream)
{
    const float* h   = (const float*)d_in[0];
    const int*   ei  = (const int*)  d_in[1];
    const float* ea  = (const float*)d_in[2];
    const float* Wq  = (const float*)d_in[3];
    const float* Wk  = (const float*)d_in[4];
    const float* Wv  = (const float*)d_in[5];
    const float* We  = (const float*)d_in[6];
    const float* Wb  = (const float*)d_in[7];
    const float* bbv = (const float*)d_in[8];
    const float* g1  = (const float*)d_in[9];
    const float* be1 = (const float*)d_in[10];
    const float* W1  = (const float*)d_in[11];
    const float* b1  = (const float*)d_in[12];
    const float* W2  = (const float*)d_in[13];
    const float* b2  = (const float*)d_in[14];
    const float* g2  = (const float*)d_in[15];
    const float* be2 = (const float*)d_in[16];
    float* out = (float*)d_out;

    const int N   = in_sizes[0] / 128;
    const int EDG = in_sizes[1] / 2;
    const int NB  = (N + 1023) / 1024;
    const size_t nd = (size_t)N * 128;
    auto al8 = [](size_t v){ return (v + 7) & ~(size_t)7; };

    float* ws = (float*)d_ws;
    const size_t Qo  = 0;                            // Qb; reused as z after fused_attn
    const size_t Ko  = nd;                           // Kb
    const size_t Vo  = 2 * nd;                       // Vb
    const size_t Xo  = 3 * nd;                       // x (attn output)
    const size_t ELo = 4 * nd;                       // elist (EDG int2)
    const size_t OFo = ELo + (size_t)EDG * 2;        // offs (N+1 int)
    const size_t CUo = al8(OFo + (size_t)N + 8);     // counts (N int)
    const size_t BSo = al8(CUo + (size_t)N);         // block sums (NB int)
    const size_t BBo = al8(BSo + (size_t)NB);        // block bases (NB int)
    const size_t STo = al8(BBo + (size_t)NB);        // stats: 512 f32
    const size_t PAR = STo + 512;                    // bn params: 512 f32
    const size_t WES = PAR + 512;                    // WeS 16384 us = 8192 f32
    const size_t WBS = WES + 8192;                   // WbS 2048 us = 1024 f32
    const size_t WQB = WBS + 1024;                   // Wqb 8192 f32
    const size_t WKB = WQB + 8192;
    const size_t WVB = WKB + 8192;
    const size_t W1B = WVB + 8192;                   // W1b 32768 us = 16384 f32
    const size_t W2B = W1B + 16384;

    int*  cnt   = (int*)(ws + CUo);
    int*  offs  = (int*)(ws + OFo);
    int*  bsum  = (int*)(ws + BSo);
    int*  bbase = (int*)(ws + BBo);
    int2* elist = (int2*)(ws + ELo);
    unsigned short* weS = (unsigned short*)(ws + WES);
    unsigned short* wbS = (unsigned short*)(ws + WBS);
    unsigned short* wqb = (unsigned short*)(ws + WQB);
    unsigned short* wkb = (unsigned short*)(ws + WKB);
    unsigned short* wvb = (unsigned short*)(ws + WVB);
    unsigned short* w1b = (unsigned short*)(ws + W1B);
    unsigned short* w2b = (unsigned short*)(ws + W2B);

    hipMemsetAsync(cnt, 0, (size_t)N * sizeof(int), stream);
    hipMemsetAsync(ws + STo, 0, 512 * sizeof(float), stream);

    convert_w<<<128, 256, 0, stream>>>(We, Wb, Wq, Wk, Wv, W1, W2,
                                       weS, wbS, wqb, wkb, wvb, w1b, w2b);

    qkv_mfma<<<(N + 63) / 64, 256, 0, stream>>>(h, wqb, wkb, wvb,
                                                ws + Qo, ws + Ko, ws + Vo, N);

    hist_kernel<<<1024, 256, 0, stream>>>(ei, cnt, EDG);
    scan_a<<<NB, 1024, 0, stream>>>(cnt, bsum, N);
    scan_b<<<1, 64, 0, stream>>>(bsum, bbase, offs, NB, N);
    scan_c<<<NB, 1024, 0, stream>>>(cnt, bbase, offs, N);
    scatter_kernel<<<1024, 256, 0, stream>>>(ei, offs, cnt, elist, EDG);

    fused_attn<<<768, 256, 0, stream>>>(ea, elist, offs, weS, wbS, bbv,
                                        ws + Qo, ws + Ko, ws + Vo, h,
                                        ws + Xo, ws + STo, N, EDG);

    bn_params<<<1, 128, 0, stream>>>(ws + STo, ws + STo + 128, g1, be1,
                                     ws + PAR, ws + PAR + 128, 1.0f / (float)N);
    ffn_mfma<<<(N + 63) / 64, 256, 0, stream>>>(ws + Xo, w1b, b1, w2b, b2,
                                                ws + PAR, ws + Qo,
                                                ws + STo + 256, N);
    bn_params<<<1, 128, 0, stream>>>(ws + STo + 256, ws + STo + 384, g2, be2,
                                     ws + PAR + 256, ws + PAR + 384, 1.0f / (float)N);
    final_bn<<<1024, 256, 0, stream>>>((const float4*)(ws + Qo), ws + PAR + 256,
                                       ws + PAR + 384, (float4*)out, N * 32);
}